// Round 17
// baseline (244.572 us; speedup 1.0000x reference)
//
#include <hip/hip_runtime.h>
#include <hip/hip_bf16.h>

typedef __bf16 bf16x8 __attribute__((ext_vector_type(8)));
typedef int   i32x8 __attribute__((ext_vector_type(8)));
typedef float f32x4 __attribute__((ext_vector_type(4)));

#define KDIM 512
#define NDIM 1024
#define DDIM 256
#define TDIM 512
#define MDIM 2048
#define NROWS 16384          // B*T type_flat rows
#define NEGV -1e10f
#define NLM 128              // lm blocks fused at the front of the main grid
#define WARR 524288          // byte offset of V-array in permuted weights

__device__ __forceinline__ unsigned int pk8(float a, float b, float c, float d) {
    unsigned int p = (unsigned int)__builtin_amdgcn_cvt_pk_fp8_f32(a, b, 0, 0);
    return (unsigned int)__builtin_amdgcn_cvt_pk_fp8_f32(c, d, (int)p, 1);
}

typedef const __attribute__((address_space(1))) unsigned int* gas_p;
typedef __attribute__((address_space(3))) unsigned int* las_p;
__device__ __forceinline__ void gl2lds16(const void* g, void* l) {
    __builtin_amdgcn_global_load_lds((gas_p)g, (las_p)l, 16, 0, 0);
}

// ---------------------------------------------------------------------------
// prep_all: one launch, three roles by blockIdx.  (R14-proven, unchanged)
// ---------------------------------------------------------------------------
__global__ void prep_all(const float* __restrict__ tok,
                         const float* __restrict__ Wg,
                         const float* __restrict__ Wv,
                         const int* __restrict__ bp,
                         unsigned char* __restrict__ tf8,
                         unsigned char* __restrict__ wp8,
                         int* __restrict__ counts,
                         unsigned short* __restrict__ lists) {
    const int bid = blockIdx.x;
    const int tid = threadIdx.x;
    if (bid < 4096) {
        int g = (bid * 256 + tid) * 4;
        int i = g >> 8, c = g & 255;
        float4 v = *(const float4*)(tok + (size_t)i * 1024 + c);
        *(unsigned int*)(tf8 + g) = pk8(v.x, v.y, v.z, v.w);
    } else if (bid < 4608) {
        __shared__ float tg[32][33];
        __shared__ float tv[32][33];
        int pb = bid - 4096;
        int n0 = (pb & 31) * 32, k0 = (pb >> 5) * 32;
        {
            int kk = tid >> 3, nn = (tid & 7) * 4;
            float4 g = *(const float4*)(Wg + (size_t)(k0 + kk) * NDIM + n0 + nn);
            float4 v = *(const float4*)(Wv + (size_t)(k0 + kk) * NDIM + n0 + nn);
            tg[kk][nn] = g.x; tg[kk][nn + 1] = g.y; tg[kk][nn + 2] = g.z; tg[kk][nn + 3] = g.w;
            tv[kk][nn] = v.x; tv[kk][nn + 1] = v.y; tv[kk][nn + 2] = v.z; tv[kk][nn + 3] = v.w;
        }
        __syncthreads();
        int nn2 = tid >> 3, kk2 = (tid & 7) * 4;
        unsigned int pg = pk8(tg[kk2][nn2], tg[kk2 + 1][nn2],
                              tg[kk2 + 2][nn2], tg[kk2 + 3][nn2]);
        unsigned int pv = pk8(tv[kk2][nn2], tv[kk2 + 1][nn2],
                              tv[kk2 + 2][nn2], tv[kk2 + 3][nn2]);
        int n = n0 + nn2, k = k0 + kk2;
        int nt = n >> 6, wn = (n >> 5) & 1, ni = (n >> 4) & 1, cp = n & 15;
        int kc = k >> 7, rem = k & 127, qq = rem >> 5, hh = (rem >> 4) & 1, bb = rem & 15;
        int frag = ((nt * 4 + kc) * 2 + wn) * 2 + ni;
        size_t off = (size_t)frag * 2048 + (qq * 16 + cp) * 32 + hh * 16 + bb;
        *(unsigned int*)(wp8 + off) = pg;
        *(unsigned int*)(wp8 + WARR + off) = pv;
    } else {
        __shared__ int c[32];
        if (tid < 32) c[tid] = 0;
        __syncthreads();
        for (int m = tid; m < MDIM; m += 256) {
            int b = bp[m];
            int pos = atomicAdd(&c[b], 1);
            lists[b * MDIM + pos] = (unsigned short)m;
        }
        __syncthreads();
        if (tid < 32) counts[tid] = c[tid];
    }
}

// ---------------------------------------------------------------------------
// fused_main: blocks [0,NLM) = lm_preds gather-GEMM MX-fp8 (R14-proven);
// blocks [NLM,..) = lemma MX-fp8 dual GEMM — R17 WAVE REMAP:
//   wave w owns m-rows [w*32, w*32+32) x ALL 64 n.  All 4 waves read the
//   SAME B fragments in lockstep -> L1 broadcast (was 2x duplicated L2
//   traffic with the wm/wn split), A-LDS fragments read by exactly one wave
//   (halved LDS traffic), and each wave owns its rows exclusively -> direct
//   global writes, NO cross-wave reduction, no sRed barriers.
//   K-loop: 8 sub-steps/nt of (4 B-loads, dbuf) -> 8 MFMAs; same 64-reg
//   B dbuf + 64-reg dual acc as the proven R14 config.
// ---------------------------------------------------------------------------
__launch_bounds__(256, 2)
__global__ void fused_main(const unsigned char* __restrict__ tf8,
                           const unsigned char* __restrict__ wp8,
                           const float* __restrict__ Wo,
                           const int* __restrict__ scope,
                           const int* __restrict__ goal,
                           float* __restrict__ outLem, int E,
                           const float* __restrict__ tok,
                           const int* __restrict__ lmi,
                           const int* __restrict__ counts,
                           const unsigned short* __restrict__ lists,
                           const int* __restrict__ tpm,
                           float* __restrict__ outP) {
    __shared__ unsigned char sA[64 * 1024];   // 64 regions x 1 KB, key (w,mi,kc,j)

    const int tid = threadIdx.x;
    const int lane = tid & 63;
    const int w = tid >> 6;
    const int col = lane & 15;
    const int q = lane >> 4;

    if ((int)blockIdx.x < NLM) {
        // ------------- lm_preds gather-GEMM, MX-fp8 (R14-proven) -------------
        const int lb = blockIdx.x;
        const int b = lb & 31;
        const int t0 = (lb >> 5) * 128;
        const int cnt = counts[b];
        for (int mt = w * 16; mt < cnt; mt += 64) {
            int mc = mt + col;
            int aid = lists[b * MDIM + (mc < cnt ? mc : cnt - 1)];
            const float* arow = tok + (size_t)lmi[aid] * DDIM;
            i32x8 af[2];
#pragma unroll
            for (int kc = 0; kc < 2; kc++) {
                unsigned int d[8];
#pragma unroll
                for (int j = 0; j < 8; j++) {
                    float4 v = *(const float4*)(arow + kc * 128 + q * 32 + j * 4);
                    d[j] = pk8(v.x, v.y, v.z, v.w);
                }
                af[kc] = (i32x8){(int)d[0], (int)d[1], (int)d[2], (int)d[3],
                                 (int)d[4], (int)d[5], (int)d[6], (int)d[7]};
            }
            int gm[4];
#pragma unroll
            for (int r = 0; r < 4; r++) {
                int mrow = mt + q * 4 + r;
                gm[r] = (mrow < cnt) ? (int)lists[b * MDIM + mrow] : -1;
            }
#pragma unroll
            for (int ntile = 0; ntile < 8; ntile++) {
                int t = t0 + ntile * 16 + col;
                const unsigned char* brow = tf8 + (size_t)(b * TDIM + t) * DDIM;
                f32x4 acc = (f32x4){0.f, 0.f, 0.f, 0.f};
#pragma unroll
                for (int kc = 0; kc < 2; kc++) {
                    uint4 lo = *(const uint4*)(brow + kc * 128 + q * 32);
                    uint4 hi = *(const uint4*)(brow + kc * 128 + q * 32 + 16);
                    i32x8 bf = (i32x8){(int)lo.x, (int)lo.y, (int)lo.z, (int)lo.w,
                                       (int)hi.x, (int)hi.y, (int)hi.z, (int)hi.w};
                    acc = __builtin_amdgcn_mfma_scale_f32_16x16x128_f8f6f4(
                        af[kc], bf, acc, 0, 0, 0, 0x7F7F7F7F, 0, 0x7F7F7F7F);
                }
                int pmv = tpm[b * TDIM + t];
#pragma unroll
                for (int r = 0; r < 4; r++) {
                    if (gm[r] >= 0)
                        outP[(size_t)gm[r] * TDIM + t] = pmv ? acc[r] : NEGV;
                }
            }
        }
        return;
    }

    // ------------------------- lemma MX-fp8 GEMM -------------------------
    const int bx = blockIdx.x - NLM;
    const int etile = bx * 128;

    // ---- stage A once: wave w stages ITS OWN 16 regions (rows w*32..+32) ----
    // region r = ((w*2+mi)*4+kc)*2+j
#pragma unroll
    for (int i = 0; i < 16; i++) {
        int r = w * 16 + i;
        int j = i & 1, kc = (i >> 1) & 3, mi = (i >> 3) & 1;
        int row = w * 32 + mi * 16 + col;
        int e = etile + row;
        int id = (e < E) ? ((kc < 2) ? scope[e] : goal[e]) : 0;
        gl2lds16(tf8 + (size_t)id * DDIM + (kc & 1) * 128 + q * 32 + j * 16,
                 &sA[r * 1024]);
    }
    __syncthreads();   // DMA completion (waves read only their own regions)

    float lem[8];
#pragma unroll
    for (int i = 0; i < 8; i++) lem[i] = 0.f;

    const unsigned char* wbase = wp8 + lane * 32;

    // B sub-step loader: t = ((nt*4+kc)*2+nh); frag = (t*2+ni)
    // overrun t=128 reads into V-array / counts region (valid memory).
#define LOADB(t, buf)                                                          \
    {                                                                          \
        _Pragma("unroll")                                                      \
        for (int ni_ = 0; ni_ < 2; ni_++) {                                    \
            size_t f_ = (size_t)((t) * 2 + ni_) * 2048;                        \
            uint4 lo_ = *(const uint4*)(wbase + f_);                           \
            uint4 hi_ = *(const uint4*)(wbase + f_ + 16);                      \
            bgb[buf][ni_] = (i32x8){(int)lo_.x, (int)lo_.y, (int)lo_.z,        \
                (int)lo_.w, (int)hi_.x, (int)hi_.y, (int)hi_.z, (int)hi_.w};   \
            lo_ = *(const uint4*)(wbase + WARR + f_);                          \
            hi_ = *(const uint4*)(wbase + WARR + f_ + 16);                     \
            bvb[buf][ni_] = (i32x8){(int)lo_.x, (int)lo_.y, (int)lo_.z,        \
                (int)lo_.w, (int)hi_.x, (int)hi_.y, (int)hi_.z, (int)hi_.w};   \
        }                                                                      \
    }

    i32x8 bgb[2][2], bvb[2][2];
    LOADB(0, 0)

    for (int nt = 0; nt < 16; nt++) {
        f32x4 accG[2][2][2], accV[2][2][2];    // [mi][nh][ni]
#pragma unroll
        for (int mi = 0; mi < 2; mi++)
#pragma unroll
            for (int nh = 0; nh < 2; nh++)
#pragma unroll
                for (int ni = 0; ni < 2; ni++) {
                    accG[mi][nh][ni] = (f32x4){0.f, 0.f, 0.f, 0.f};
                    accV[mi][nh][ni] = (f32x4){0.f, 0.f, 0.f, 0.f};
                }
#pragma unroll
        for (int kc = 0; kc < 4; kc++) {
            // A fragments for this kc (per-wave-private LDS, conflict-free)
            i32x8 af[2];
#pragma unroll
            for (int mi = 0; mi < 2; mi++) {
                int rb = ((w * 2 + mi) * 4 + kc) * 2;
                uint4 lo = *(const uint4*)(&sA[rb * 1024 + lane * 16]);
                uint4 hi = *(const uint4*)(&sA[(rb + 1) * 1024 + lane * 16]);
                af[mi] = (i32x8){(int)lo.x, (int)lo.y, (int)lo.z, (int)lo.w,
                                 (int)hi.x, (int)hi.y, (int)hi.z, (int)hi.w};
            }
#pragma unroll
            for (int nh = 0; nh < 2; nh++) {
                const int t = (nt * 4 + kc) * 2 + nh;
                const int cur = t & 1, nxt = cur ^ 1;
                LOADB(t + 1, nxt)              // prefetch next sub-step's B
#pragma unroll
                for (int mi = 0; mi < 2; mi++)
#pragma unroll
                    for (int ni = 0; ni < 2; ni++) {
                        accG[mi][nh][ni] = __builtin_amdgcn_mfma_scale_f32_16x16x128_f8f6f4(
                            af[mi], bgb[cur][ni], accG[mi][nh][ni], 0, 0, 0,
                            0x7F7F7F7F, 0, 0x7F7F7F7F);
                        accV[mi][nh][ni] = __builtin_amdgcn_mfma_scale_f32_16x16x128_f8f6f4(
                            af[mi], bvb[cur][ni], accV[mi][nh][ni], 0, 0, 0,
                            0x7F7F7F7F, 0, 0x7F7F7F7F);
                    }
            }
        }
        // epilogue: lem += silu(G)*V*Wo[n]  (exp+rcpf, R14-proven)
#pragma unroll
        for (int nh = 0; nh < 2; nh++)
#pragma unroll
            for (int ni = 0; ni < 2; ni++) {
                float wo = Wo[nt * 64 + nh * 32 + ni * 16 + col];
#pragma unroll
                for (int mi = 0; mi < 2; mi++)
#pragma unroll
                    for (int r = 0; r < 4; r++) {
                        float g = accG[mi][nh][ni][r];
                        float v = accV[mi][nh][ni][r];
                        float s = g * __builtin_amdgcn_rcpf(1.f + __expf(-g));
                        lem[mi * 4 + r] += s * v * wo;
                    }
            }
    }
    // reduce across the 16 N-cols; wave owns its rows -> direct global write
#pragma unroll
    for (int i = 0; i < 8; i++) {
        float v = lem[i];
        for (int off = 8; off > 0; off >>= 1) v += __shfl_xor(v, off, 16);
        if (col == 0) {
            int e = etile + w * 32 + (i >> 2) * 16 + q * 4 + (i & 3);
            if (e < E) outLem[e] = v;
        }
    }
}

extern "C" void kernel_launch(void* const* d_in, const int* in_sizes, int n_in,
                              void* d_out, int out_size, void* d_ws, size_t ws_size,
                              hipStream_t stream) {
    const float* tok = (const float*)d_in[0];
    const float* Wg  = (const float*)d_in[1];
    const float* Wv  = (const float*)d_in[2];
    const float* Wo  = (const float*)d_in[3];
    const int* edge = (const int*)d_in[4];
    const int* lmi  = (const int*)d_in[5];
    const int* bp   = (const int*)d_in[6];
    const int* tpm  = (const int*)d_in[7];
    const int E = in_sizes[4] / 2;           // 100000
    float* out = (float*)d_out;

    // workspace layout (~5.2 MB)
    unsigned char* tf8 = (unsigned char*)d_ws;                 // 4 MB
    unsigned char* wp8 = tf8 + (size_t)NROWS * DDIM;           // 1 MB (G+V)
    int* counts = (int*)(wp8 + 2 * WARR);                      // 128 B
    unsigned short* lists = (unsigned short*)(counts + 32);    // 128 KB

    prep_all<<<dim3(4609), dim3(256), 0, stream>>>(
        tok, Wg, Wv, bp, tf8, wp8, counts, lists);
    int nLemBlocks = (E + 127) / 128;        // 782
    fused_main<<<dim3(NLM + nLemBlocks), dim3(256), 0, stream>>>(
        tf8, wp8, Wo, edge, edge + E, out, E,
        tok, lmi, counts, lists, tpm, out + E);
}

// Round 18
// 229.720 us; speedup vs baseline: 1.0647x; 1.0647x over previous
//
#include <hip/hip_runtime.h>
#include <hip/hip_bf16.h>

typedef __bf16 bf16x8 __attribute__((ext_vector_type(8)));
typedef int   i32x8 __attribute__((ext_vector_type(8)));
typedef float f32x4 __attribute__((ext_vector_type(4)));

#define KDIM 512
#define NDIM 1024
#define DDIM 256
#define TDIM 512
#define MDIM 2048
#define NROWS 16384          // B*T type_flat rows
#define NEGV -1e10f
#define NLM 128              // lm blocks fused at the front of the main grid
#define WARR 524288          // byte offset of V-array in permuted weights

__device__ __forceinline__ unsigned int pk8(float a, float b, float c, float d) {
    unsigned int p = (unsigned int)__builtin_amdgcn_cvt_pk_fp8_f32(a, b, 0, 0);
    return (unsigned int)__builtin_amdgcn_cvt_pk_fp8_f32(c, d, (int)p, 1);
}

typedef const __attribute__((address_space(1))) unsigned int* gas_p;
typedef __attribute__((address_space(3))) unsigned int* las_p;
__device__ __forceinline__ void gl2lds16(const void* g, void* l) {
    __builtin_amdgcn_global_load_lds((gas_p)g, (las_p)l, 16, 0, 0);
}

// ---------------------------------------------------------------------------
// prep_all: one launch, three roles by blockIdx.  (R14/R16-proven)
// ---------------------------------------------------------------------------
__global__ void prep_all(const float* __restrict__ tok,
                         const float* __restrict__ Wg,
                         const float* __restrict__ Wv,
                         const int* __restrict__ bp,
                         unsigned char* __restrict__ tf8,
                         unsigned char* __restrict__ wp8,
                         int* __restrict__ counts,
                         unsigned short* __restrict__ lists) {
    const int bid = blockIdx.x;
    const int tid = threadIdx.x;
    if (bid < 4096) {
        int g = (bid * 256 + tid) * 4;
        int i = g >> 8, c = g & 255;
        float4 v = *(const float4*)(tok + (size_t)i * 1024 + c);
        *(unsigned int*)(tf8 + g) = pk8(v.x, v.y, v.z, v.w);
    } else if (bid < 4608) {
        __shared__ float tg[32][33];
        __shared__ float tv[32][33];
        int pb = bid - 4096;
        int n0 = (pb & 31) * 32, k0 = (pb >> 5) * 32;
        {
            int kk = tid >> 3, nn = (tid & 7) * 4;
            float4 g = *(const float4*)(Wg + (size_t)(k0 + kk) * NDIM + n0 + nn);
            float4 v = *(const float4*)(Wv + (size_t)(k0 + kk) * NDIM + n0 + nn);
            tg[kk][nn] = g.x; tg[kk][nn + 1] = g.y; tg[kk][nn + 2] = g.z; tg[kk][nn + 3] = g.w;
            tv[kk][nn] = v.x; tv[kk][nn + 1] = v.y; tv[kk][nn + 2] = v.z; tv[kk][nn + 3] = v.w;
        }
        __syncthreads();
        int nn2 = tid >> 3, kk2 = (tid & 7) * 4;
        unsigned int pg = pk8(tg[kk2][nn2], tg[kk2 + 1][nn2],
                              tg[kk2 + 2][nn2], tg[kk2 + 3][nn2]);
        unsigned int pv = pk8(tv[kk2][nn2], tv[kk2 + 1][nn2],
                              tv[kk2 + 2][nn2], tv[kk2 + 3][nn2]);
        int n = n0 + nn2, k = k0 + kk2;
        int nt = n >> 6, wn = (n >> 5) & 1, ni = (n >> 4) & 1, cp = n & 15;
        int kc = k >> 7, rem = k & 127, qq = rem >> 5, hh = (rem >> 4) & 1, bb = rem & 15;
        int frag = ((nt * 4 + kc) * 2 + wn) * 2 + ni;
        size_t off = (size_t)frag * 2048 + (qq * 16 + cp) * 32 + hh * 16 + bb;
        *(unsigned int*)(wp8 + off) = pg;
        *(unsigned int*)(wp8 + WARR + off) = pv;
    } else {
        __shared__ int c[32];
        if (tid < 32) c[tid] = 0;
        __syncthreads();
        for (int m = tid; m < MDIM; m += 256) {
            int b = bp[m];
            int pos = atomicAdd(&c[b], 1);
            lists[b * MDIM + pos] = (unsigned short)m;
        }
        __syncthreads();
        if (tid < 32) counts[tid] = c[tid];
    }
}

// ---------------------------------------------------------------------------
// fused_main — EXACT R14/R16 (best verified: fused 146us, total 229.8us):
// blocks [0,NLM): lm_preds gather-GEMM MX-fp8 (B direct from tf8, A cvt in
// regs); blocks [NLM,..): lemma MX-fp8 dual GEMM — M=128, (256,2) [(256,3)
// spills: R3/R13], barrier-free K-loop, B register double-buffer (1-full-step
// prefetch = the latency-hiding currency; halving it regressed — R17),
// fragment-ordered conflict-free staging, exp+rcpf silu (hard-sigmoid
// regressed — R15; wm/wn split beats wave-remap — R17).
// ---------------------------------------------------------------------------
__launch_bounds__(256, 2)
__global__ void fused_main(const unsigned char* __restrict__ tf8,
                           const unsigned char* __restrict__ wp8,
                           const float* __restrict__ Wo,
                           const int* __restrict__ scope,
                           const int* __restrict__ goal,
                           float* __restrict__ outLem, int E,
                           const float* __restrict__ tok,
                           const int* __restrict__ lmi,
                           const int* __restrict__ counts,
                           const unsigned short* __restrict__ lists,
                           const int* __restrict__ tpm,
                           float* __restrict__ outP) {
    __shared__ unsigned char sA[64 * 1024];   // 64 regions x 1 KB, key (am,mi,kc,j)
    __shared__ float sRed[256];

    const int tid = threadIdx.x;
    const int lane = tid & 63;
    const int w = tid >> 6;
    const int col = lane & 15;
    const int q = lane >> 4;

    if ((int)blockIdx.x < NLM) {
        // ------------- lm_preds gather-GEMM, MX-fp8 (R14-proven) -------------
        const int lb = blockIdx.x;
        const int b = lb & 31;
        const int t0 = (lb >> 5) * 128;
        const int cnt = counts[b];
        for (int mt = w * 16; mt < cnt; mt += 64) {
            int mc = mt + col;
            int aid = lists[b * MDIM + (mc < cnt ? mc : cnt - 1)];
            const float* arow = tok + (size_t)lmi[aid] * DDIM;
            i32x8 af[2];
#pragma unroll
            for (int kc = 0; kc < 2; kc++) {
                unsigned int d[8];
#pragma unroll
                for (int j = 0; j < 8; j++) {
                    float4 v = *(const float4*)(arow + kc * 128 + q * 32 + j * 4);
                    d[j] = pk8(v.x, v.y, v.z, v.w);
                }
                af[kc] = (i32x8){(int)d[0], (int)d[1], (int)d[2], (int)d[3],
                                 (int)d[4], (int)d[5], (int)d[6], (int)d[7]};
            }
            int gm[4];
#pragma unroll
            for (int r = 0; r < 4; r++) {
                int mrow = mt + q * 4 + r;
                gm[r] = (mrow < cnt) ? (int)lists[b * MDIM + mrow] : -1;
            }
#pragma unroll
            for (int ntile = 0; ntile < 8; ntile++) {
                int t = t0 + ntile * 16 + col;
                const unsigned char* brow = tf8 + (size_t)(b * TDIM + t) * DDIM;
                f32x4 acc = (f32x4){0.f, 0.f, 0.f, 0.f};
#pragma unroll
                for (int kc = 0; kc < 2; kc++) {
                    uint4 lo = *(const uint4*)(brow + kc * 128 + q * 32);
                    uint4 hi = *(const uint4*)(brow + kc * 128 + q * 32 + 16);
                    i32x8 bf = (i32x8){(int)lo.x, (int)lo.y, (int)lo.z, (int)lo.w,
                                       (int)hi.x, (int)hi.y, (int)hi.z, (int)hi.w};
                    acc = __builtin_amdgcn_mfma_scale_f32_16x16x128_f8f6f4(
                        af[kc], bf, acc, 0, 0, 0, 0x7F7F7F7F, 0, 0x7F7F7F7F);
                }
                int pmv = tpm[b * TDIM + t];
#pragma unroll
                for (int r = 0; r < 4; r++) {
                    if (gm[r] >= 0)
                        outP[(size_t)gm[r] * TDIM + t] = pmv ? acc[r] : NEGV;
                }
            }
        }
        return;
    }

    // ------------------- lemma MX-fp8 GEMM (R12/R14 config) -------------------
    const int bx = blockIdx.x - NLM;
    const int etile = bx * 128;
    const int wm = w & 1;      // m-half (64 rows)
    const int wn = w >> 1;     // n-half (32 of the 64-wide n-tile)

    // ---- stage A once: 64 fragment-ordered regions, 16 per wave ----
#pragma unroll
    for (int i = 0; i < 16; i++) {
        int r = w * 16 + i;
        int j = r & 1, kc = (r >> 1) & 3, mi = (r >> 3) & 3, am = r >> 5;
        int row = am * 64 + mi * 16 + col;
        int e = etile + row;
        int id = (e < E) ? ((kc < 2) ? scope[e] : goal[e]) : 0;
        gl2lds16(tf8 + (size_t)id * DDIM + (kc & 1) * 128 + q * 32 + j * 16,
                 &sA[r * 1024]);
    }
    __syncthreads();   // the ONLY barrier before the reduction

    float lem[16];
#pragma unroll
    for (int i = 0; i < 16; i++) lem[i] = 0.f;

    const unsigned char* wbase = wp8 + lane * 32;

#define LOADB(s, buf)                                                          \
    {                                                                          \
        _Pragma("unroll")                                                      \
        for (int ni_ = 0; ni_ < 2; ni_++) {                                    \
            size_t f_ = (size_t)(((s) * 2 + wn) * 2 + ni_) * 2048;             \
            uint4 lo_ = *(const uint4*)(wbase + f_);                           \
            uint4 hi_ = *(const uint4*)(wbase + f_ + 16);                      \
            bgb[buf][ni_] = (i32x8){(int)lo_.x, (int)lo_.y, (int)lo_.z,        \
                (int)lo_.w, (int)hi_.x, (int)hi_.y, (int)hi_.z, (int)hi_.w};   \
            lo_ = *(const uint4*)(wbase + WARR + f_);                          \
            hi_ = *(const uint4*)(wbase + WARR + f_ + 16);                     \
            bvb[buf][ni_] = (i32x8){(int)lo_.x, (int)lo_.y, (int)lo_.z,        \
                (int)lo_.w, (int)hi_.x, (int)hi_.y, (int)hi_.z, (int)hi_.w};   \
        }                                                                      \
    }

    i32x8 bgb[2][2], bvb[2][2];
    LOADB(0, 0)

    for (int nt = 0; nt < 16; nt++) {
        f32x4 accG[4][2], accV[4][2];
#pragma unroll
        for (int mi = 0; mi < 4; mi++)
#pragma unroll
            for (int ni = 0; ni < 2; ni++) {
                accG[mi][ni] = (f32x4){0.f, 0.f, 0.f, 0.f};
                accV[mi][ni] = (f32x4){0.f, 0.f, 0.f, 0.f};
            }
#pragma unroll
        for (int kc = 0; kc < 4; kc++) {
            const int cur = kc & 1, nxt = cur ^ 1;
            LOADB(nt * 4 + kc + 1, nxt)        // prefetch next step's B
#pragma unroll
            for (int mi = 0; mi < 4; mi++) {
                int rb = ((wm * 4 + mi) * 4 + kc) * 2;
                uint4 lo = *(const uint4*)(&sA[rb * 1024 + lane * 16]);
                uint4 hi = *(const uint4*)(&sA[(rb + 1) * 1024 + lane * 16]);
                i32x8 af = (i32x8){(int)lo.x, (int)lo.y, (int)lo.z, (int)lo.w,
                                   (int)hi.x, (int)hi.y, (int)hi.z, (int)hi.w};
#pragma unroll
                for (int ni = 0; ni < 2; ni++) {
                    accG[mi][ni] = __builtin_amdgcn_mfma_scale_f32_16x16x128_f8f6f4(
                        af, bgb[cur][ni], accG[mi][ni], 0, 0, 0,
                        0x7F7F7F7F, 0, 0x7F7F7F7F);
                    accV[mi][ni] = __builtin_amdgcn_mfma_scale_f32_16x16x128_f8f6f4(
                        af, bvb[cur][ni], accV[mi][ni], 0, 0, 0,
                        0x7F7F7F7F, 0, 0x7F7F7F7F);
                }
            }
        }
        // epilogue: lem += silu(G)*V*Wo[n].  exp+rcpf (R14-proven).
#pragma unroll
        for (int ni = 0; ni < 2; ni++) {
            float wo = Wo[nt * 64 + wn * 32 + ni * 16 + col];
#pragma unroll
            for (int mi = 0; mi < 4; mi++)
#pragma unroll
                for (int r = 0; r < 4; r++) {
                    float g = accG[mi][ni][r];
                    float v = accV[mi][ni][r];
                    float s = g * __builtin_amdgcn_rcpf(1.f + __expf(-g));
                    lem[mi * 4 + r] += s * v * wo;
                }
        }
    }
    // reduce across the 16 N-cols, then across the 2 n-wave halves
#pragma unroll
    for (int i = 0; i < 16; i++) {
        float v = lem[i];
        for (int off = 8; off > 0; off >>= 1) v += __shfl_xor(v, off, 16);
        if (col == 0) {
            int row = wm * 64 + (i >> 2) * 16 + q * 4 + (i & 3);
            sRed[wn * 128 + row] = v;
        }
    }
    __syncthreads();
    if (tid < 128) {
        int e = etile + tid;
        if (e < E) outLem[e] = sRed[tid] + sRed[128 + tid];
    }
}

extern "C" void kernel_launch(void* const* d_in, const int* in_sizes, int n_in,
                              void* d_out, int out_size, void* d_ws, size_t ws_size,
                              hipStream_t stream) {
    const float* tok = (const float*)d_in[0];
    const float* Wg  = (const float*)d_in[1];
    const float* Wv  = (const float*)d_in[2];
    const float* Wo  = (const float*)d_in[3];
    const int* edge = (const int*)d_in[4];
    const int* lmi  = (const int*)d_in[5];
    const int* bp   = (const int*)d_in[6];
    const int* tpm  = (const int*)d_in[7];
    const int E = in_sizes[4] / 2;           // 100000
    float* out = (float*)d_out;

    // workspace layout (~5.2 MB)
    unsigned char* tf8 = (unsigned char*)d_ws;                 // 4 MB
    unsigned char* wp8 = tf8 + (size_t)NROWS * DDIM;           // 1 MB (G+V)
    int* counts = (int*)(wp8 + 2 * WARR);                      // 128 B
    unsigned short* lists = (unsigned short*)(counts + 32);    // 128 KB

    prep_all<<<dim3(4609), dim3(256), 0, stream>>>(
        tok, Wg, Wv, bp, tf8, wp8, counts, lists);
    int nLemBlocks = (E + 127) / 128;        // 782
    fused_main<<<dim3(NLM + nLemBlocks), dim3(256), 0, stream>>>(
        tf8, wp8, Wo, edge, edge + E, out, E,
        tok, lmi, counts, lists, tpm, out + E);
}